// Round 2
// baseline (238.194 us; speedup 1.0000x reference)
//
#include <hip/hip_runtime.h>
#include <cstdint>
#include <cstddef>

typedef short short8 __attribute__((ext_vector_type(8)));
typedef float f32x4 __attribute__((ext_vector_type(4)));

#define BB 16
#define SS 512
#define TT 64
#define LL 64
#define UU 128

// ws layout (bytes) — hi-only W fragments (no emb table anymore)
#define WT_OFF    0u                      // W_trans frags: 32 x 1KB = 32KB
#define WHT_OFF   (WT_OFF + 32768u)       // W_ht frags: 64 x 1KB = 64KB
#define WREL_OFF  (WHT_OFF + 65536u)      // W_rel frags: 32 x 1KB = 32KB

__device__ __forceinline__ unsigned short f2bf(float x) {  // rtne f32->bf16
  unsigned u = __float_as_uint(x);
  unsigned r = ((u >> 16) & 1u) + 0x7FFFu;
  return (unsigned short)((u + r) >> 16);
}
__device__ __forceinline__ float ftanh(float x) {  // 1 - 2/(e^2x+1)
  float e = __expf(2.0f * x);
  return 1.0f - __fdividef(2.0f, e + 1.0f);
}
// packed rtne pair convert: lo=cvt(a), hi=cvt(b)
__device__ __forceinline__ unsigned cvtpk(float a, float b) {
  unsigned r;
  asm("v_cvt_pk_bf16_f32 %0, %1, %2" : "=v"(r) : "v"(a), "v"(b));
  return r;
}
// 16-lane (DPP row) sum — pure VALU.
__device__ __forceinline__ float row16_sum(float x) {
  x += __int_as_float(__builtin_amdgcn_update_dpp(0, __float_as_int(x), 0xB1, 0xF, 0xF, true));
  x += __int_as_float(__builtin_amdgcn_update_dpp(0, __float_as_int(x), 0x4E, 0xF, 0xF, true));
  x += __int_as_float(__builtin_amdgcn_update_dpp(0, __float_as_int(x), 0x141, 0xF, 0xF, true));
  x += __int_as_float(__builtin_amdgcn_update_dpp(0, __float_as_int(x), 0x140, 0xF, 0xF, true));
  return x;
}

// ---- prep: pack W into bf16 fragments (hi only). 32 blocks only. ----------
// Frag (16x16x32, A/B symmetric): lane l holds W[kt*32+(l>>4)*8+j][nt*16+(l&15)].
// pairIdx=(kt*8+nt): [pairIdx*1024 + lane*16].
__global__ void prep_kernel(const float* __restrict__ Wt,
                            const float* __restrict__ Wht,
                            const float* __restrict__ Wrel,
                            unsigned char* __restrict__ ws) {
  int slot = blockIdx.x * 256 + threadIdx.x;      // 8192 slots
  const float* W;
  unsigned char* base;
  if (slot < 2048)      { W = Wt;   base = ws + WT_OFF; }
  else if (slot < 6144) { W = Wht;  base = ws + WHT_OFF;  slot -= 2048; }
  else                  { W = Wrel; base = ws + WREL_OFF; slot -= 6144; }
  int lane = slot & 63, pair = slot >> 6;
  int n  = (pair & 7) * 16 + (lane & 15);
  int k0 = (pair >> 3) * 32 + (lane >> 4) * 8;
  short8 hv;
  #pragma unroll
  for (int j = 0; j < 8; ++j)
    hv[j] = (short)f2bf(W[(size_t)(k0 + j) * UU + n]);
  *reinterpret_cast<short8*>(base + (size_t)pair * 1024 + lane * 16) = hv;
}

// ---- fused kernel: 512 blocks x 1024 threads, 2 (b,t) tiles per block -----
// All 512 blocks resident (2/CU, 32 waves/CU) — single round, no drain.
// Pipeline: stage(bt1) loads ISSUED during GEMM2(bt0) tail, WRITTEN to LDS
// after wsum(bt0)'s last te read; scatter(bt0) overlaps GEMM1(bt1).
// Wave split: ntp=w&3 owns n-tiles {2ntp,2ntp+1}; grp=w>>2 owns 3 row-tiles
// (GEMM1) / 1 m-tile (GEMM2). Every LDS fragment read feeds TWO MFMAs.
// TEB swizzle: logical 16B-chunk c16 of row r at physical chunk c16^(r&15).
__launch_bounds__(1024, 8)
__global__ void fused_bt(const int* __restrict__ triples,
                         const float* __restrict__ emb_f32,
                         const float* __restrict__ b_trans,
                         const float* __restrict__ b_ht,
                         const float* __restrict__ b_rel,
                         const int* __restrict__ sent_triples,
                         const unsigned char* __restrict__ wsr,
                         float* __restrict__ out) {
  __shared__ unsigned short TEB[192 * 128];    // 48KB: emb staging -> te
  __shared__ float EWt[4][64];                 // e_weight partials (per ntp)
  __shared__ float ALPHA[64];
  __shared__ float PART[8][256];               // wsum partials (8 l-groups)
  __shared__ int MATCH[2][512];                // per sub-tile match lists
  __shared__ int NM[2];

  const int tid  = threadIdx.x;
  const int bt0  = blockIdx.x * 2;
  const int w    = tid >> 6;      // wave id 0..15
  const int lane = tid & 63;
  const int li   = lane & 15;
  const int lg   = lane >> 4;
  const int ntp  = w & 3;
  const int nt0  = ntp * 2, nt1 = nt0 + 1;
  const int grp  = w >> 2;        // 0..3
  // staged slot j of this thread covers row 4w+64j+lg, chunk li.
  const int rw15 = (4 * w + lg) & 15;                 // row&15, same for all j
  const int trow = 4 * w + 64 * (lane >> 2) + (lane & 3);  // loader-lane row

  const unsigned char* wtb  = wsr + WT_OFF;
  const unsigned char* whtb = wsr + WHT_OFF;
  const unsigned char* wrlb = wsr + WREL_OFF;

  if (tid < 2) NM[tid] = 0;

  // ---- stage bt0: 12 token loads/wave + shfl broadcast, f32 gather, cvt ---
  {
    int tk = 0;
    if (lane < 12) tk = triples[(size_t)bt0 * 192 + trow];
    float4 xv[3], yv[3];
    #pragma unroll
    for (int j = 0; j < 3; ++j) {
      int tok = __shfl(tk, 4 * j + lg, 64);
      const float* fb = emb_f32 + (size_t)tok * UU + ((li ^ rw15) << 3);
      xv[j] = *reinterpret_cast<const float4*>(fb);
      yv[j] = *reinterpret_cast<const float4*>(fb + 4);
    }
    #pragma unroll
    for (int j = 0; j < 3; ++j) {
      uint4 pk = { cvtpk(xv[j].x, xv[j].y), cvtpk(xv[j].z, xv[j].w),
                   cvtpk(yv[j].x, yv[j].y), cvtpk(yv[j].z, yv[j].w) };
      *reinterpret_cast<uint4*>(&TEB[(tid + j * 1024) * 8]) = pk;
    }
  }
  __syncthreads();  // TEB(bt0) + NM ready

  // ---- match-find for BOTH sub-tiles from ONE load (overlaps GEMM1) ------
  if (tid < SS) {
    int idx = sent_triples[(size_t)(bt0 >> 6) * SS + tid];
    int t0  = bt0 & 63;
    if (idx == t0)     MATCH[0][atomicAdd(&NM[0], 1)] = tid;
    if (idx == t0 + 1) MATCH[1][atomicAdd(&NM[1], 1)] = tid;
  }

  float4 sx[3], sy[3];   // bt1 staging registers (issued in GEMM2(bt0) tail)

  #pragma unroll 1
  for (int it = 0; it < 2; ++it) {
    // ============ GEMM1: 3 row-tiles x 2 n-tiles ==========================
    f32x4 acc[3][2];
    #pragma unroll
    for (int q = 0; q < 3; ++q) {
      acc[q][0] = f32x4{0.f, 0.f, 0.f, 0.f};
      acc[q][1] = f32x4{0.f, 0.f, 0.f, 0.f};
    }
    #pragma unroll
    for (int kt = 0; kt < 4; ++kt) {
      const short8 Wa = *reinterpret_cast<const short8*>(
          wtb + (size_t)(kt * 8 + nt0) * 1024 + lane * 16);
      const short8 Wb = *reinterpret_cast<const short8*>(
          wtb + (size_t)(kt * 8 + nt1) * 1024 + lane * 16);
      #pragma unroll
      for (int q = 0; q < 3; ++q) {
        const short8 bfr = *reinterpret_cast<const short8*>(
            &TEB[((grp * 3 + q) * 16 + li) * 128 + (((kt * 4 + lg) ^ li) << 3)]);
        acc[q][0] = __builtin_amdgcn_mfma_f32_16x16x32_bf16(Wa, bfr, acc[q][0], 0, 0, 0);
        acc[q][1] = __builtin_amdgcn_mfma_f32_16x16x32_bf16(Wb, bfr, acc[q][1], 0, 0, 0);
      }
    }
    __syncthreads();  // ALL emb reads complete before any te overwrite

    // ============ GEMM1 epilogue: te in one pass ==========================
    {
      const float4 btrA = *reinterpret_cast<const float4*>(b_trans + nt0 * 16 + lg * 4);
      const float4 btrB = *reinterpret_cast<const float4*>(b_trans + nt1 * 16 + lg * 4);
      const int hb8  = (lg & 1) << 3;
      const int cc8A = nt0 * 2 + (lg >> 1);
      const int cc8B = cc8A + 2;
      #pragma unroll
      for (int q = 0; q < 3; ++q) {
        int row = (grp * 3 + q) * 16 + li;   // row & 15 == li
        char* base = reinterpret_cast<char*>(TEB) + row * 256;
        {
          float v0 = ftanh(acc[q][0][0] + btrA.x);
          float v1 = ftanh(acc[q][0][1] + btrA.y);
          float v2 = ftanh(acc[q][0][2] + btrA.z);
          float v3 = ftanh(acc[q][0][3] + btrA.w);
          uint2 pk = { cvtpk(v0, v1), cvtpk(v2, v3) };
          *reinterpret_cast<uint2*>(base + (((cc8A ^ li) << 4) | hb8)) = pk;
        }
        {
          float v0 = ftanh(acc[q][1][0] + btrB.x);
          float v1 = ftanh(acc[q][1][1] + btrB.y);
          float v2 = ftanh(acc[q][1][2] + btrB.z);
          float v3 = ftanh(acc[q][1][3] + btrB.w);
          uint2 pk = { cvtpk(v0, v1), cvtpk(v2, v3) };
          *reinterpret_cast<uint2*>(base + (((cc8B ^ li) << 4) | hb8)) = pk;
        }
      }
    }
    // prefetch GEMM2 first W pair before the barrier
    short8 Wc0 = *reinterpret_cast<const short8*>(whtb + (size_t)nt0 * 1024 + lane * 16);
    short8 Wc1 = *reinterpret_cast<const short8*>(whtb + (size_t)nt1 * 1024 + lane * 16);
    __syncthreads();  // te complete

    // ============ GEMM2: 1 m-tile x 2 n-tiles =============================
    int tk1 = 0;                         // bt1 tokens: issue EARLY (latency)
    if (it == 0 && lane < 12)
      tk1 = triples[(size_t)(bt0 + 1) * 192 + trow];

    const int rowb = 48 * grp + 3 * li;
    f32x4 aH0{0.f,0.f,0.f,0.f}, aH1{0.f,0.f,0.f,0.f};
    f32x4 aR0{0.f,0.f,0.f,0.f}, aR1{0.f,0.f,0.f,0.f};

    #pragma unroll
    for (int kt = 0; kt < 8; ++kt) {   // head_tail: K=256
      short8 Wn0, Wn1;
      if (kt < 7) {
        Wn0 = *reinterpret_cast<const short8*>(
            whtb + (size_t)((kt + 1) * 8 + nt0) * 1024 + lane * 16);
        Wn1 = *reinterpret_cast<const short8*>(
            whtb + (size_t)((kt + 1) * 8 + nt1) * 1024 + lane * 16);
      } else {
        Wn0 = *reinterpret_cast<const short8*>(wrlb + (size_t)nt0 * 1024 + lane * 16);
        Wn1 = *reinterpret_cast<const short8*>(wrlb + (size_t)nt1 * 1024 + lane * 16);
      }
      const int row = rowb + ((kt < 4) ? 0 : 2);
      const int c16 = (kt & 3) * 4 + lg;
      const short8 a = *reinterpret_cast<const short8*>(
          &TEB[row * 128 + ((c16 ^ (row & 15)) << 3)]);
      aH0 = __builtin_amdgcn_mfma_f32_16x16x32_bf16(a, Wc0, aH0, 0, 0, 0);
      aH1 = __builtin_amdgcn_mfma_f32_16x16x32_bf16(a, Wc1, aH1, 0, 0, 0);
      Wc0 = Wn0; Wc1 = Wn1;
    }
    #pragma unroll
    for (int kt = 0; kt < 4; ++kt) {   // relation: K=128, rows 3l+1
      short8 Wn0, Wn1;
      if (kt < 3) {
        Wn0 = *reinterpret_cast<const short8*>(
            wrlb + (size_t)((kt + 1) * 8 + nt0) * 1024 + lane * 16);
        Wn1 = *reinterpret_cast<const short8*>(
            wrlb + (size_t)((kt + 1) * 8 + nt1) * 1024 + lane * 16);
      }
      const int row = rowb + 1;
      const int c16 = kt * 4 + lg;
      const short8 a = *reinterpret_cast<const short8*>(
          &TEB[row * 128 + ((c16 ^ (row & 15)) << 3)]);
      aR0 = __builtin_amdgcn_mfma_f32_16x16x32_bf16(a, Wc0, aR0, 0, 0, 0);
      aR1 = __builtin_amdgcn_mfma_f32_16x16x32_bf16(a, Wc1, aR1, 0, 0, 0);
      if (kt < 3) { Wc0 = Wn0; Wc1 = Wn1; }
    }

    // ---- ISSUE bt1 staging gathers; latency hides under ew/softmax/wsum --
    if (it == 0) {
      #pragma unroll
      for (int j = 0; j < 3; ++j) {
        int tok = __shfl(tk1, 4 * j + lg, 64);
        const float* fb = emb_f32 + (size_t)tok * UU + ((li ^ rw15) << 3);
        sx[j] = *reinterpret_cast<const float4*>(fb);
        sy[j] = *reinterpret_cast<const float4*>(fb + 4);
      }
    }

    // e_weight partials: l = grp*16 + lg*4 + r; DPP-reduce over 16 li lanes
    {
      const float bh0 = b_ht[nt0 * 16 + li],  bh1 = b_ht[nt1 * 16 + li];
      const float br0 = b_rel[nt0 * 16 + li], br1 = b_rel[nt1 * 16 + li];
      #pragma unroll
      for (int r = 0; r < 4; ++r) {
        float p = ftanh(aH0[r] + bh0) * (aR0[r] + br0)
                + ftanh(aH1[r] + bh1) * (aR1[r] + br1);
        p = row16_sum(p);
        if (li == 0) EWt[ntp][grp * 16 + lg * 4 + r] = p;
      }
    }
    __syncthreads();

    // ============ softmax over L=64 (wave 0) ==============================
    if (tid < 64) {
      float e = EWt[0][tid] + EWt[1][tid] + EWt[2][tid] + EWt[3][tid];
      float mx = e;
      #pragma unroll
      for (int off = 32; off > 0; off >>= 1)
        mx = fmaxf(mx, __shfl_xor(mx, off, 64));
      float ex = __expf(e - mx);
      float sm = ex;
      #pragma unroll
      for (int off = 32; off > 0; off >>= 1)
        sm += __shfl_xor(sm, off, 64);
      ALPHA[tid] = ex / sm;
    }
    __syncthreads();

    // ============ weighted sum: paired-bf16 b32 reads, 8 l's per thread ===
    {
      int cp  = tid & 127, lgp = tid >> 7;   // col-pair, l-group (8 l's)
      int c0  = cp << 1;
      int k   = (c0 >> 7) << 1;              // head rows 3l, tail rows 3l+2
      int cc  = c0 & 127;
      int w8  = cc >> 3, bofs = (cc & 7) << 1;
      float4 a03 = *reinterpret_cast<const float4*>(&ALPHA[lgp * 8]);
      float4 a47 = *reinterpret_cast<const float4*>(&ALPHA[lgp * 8 + 4]);
      float o0 = 0.f, o1 = 0.f;
      #pragma unroll
      for (int j = 0; j < 8; ++j) {
        int l = lgp * 8 + j;
        int row = 3 * l + k;
        unsigned u = *reinterpret_cast<const unsigned*>(
            reinterpret_cast<const char*>(TEB) + row * 256 +
            (((w8 ^ (row & 15)) << 4) | bofs));
        float al = (j < 4) ? a03[j] : a47[j - 4];
        o0 = fmaf(al, __uint_as_float(u << 16), o0);
        o1 = fmaf(al, __uint_as_float(u & 0xFFFF0000u), o1);
      }
      *reinterpret_cast<float2*>(&PART[lgp][c0]) = make_float2(o0, o1);
    }
    __syncthreads();  // last te reads done -> TEB reusable

    // ---- WRITE bt1 staging into TEB (loads long since landed) ------------
    if (it == 0) {
      #pragma unroll
      for (int j = 0; j < 3; ++j) {
        uint4 pk = { cvtpk(sx[j].x, sx[j].y), cvtpk(sx[j].z, sx[j].w),
                     cvtpk(sy[j].x, sy[j].y), cvtpk(sy[j].z, sy[j].w) };
        *reinterpret_cast<uint4*>(&TEB[(tid + j * 1024) * 8]) = pk;
      }
    }
    if (tid < 256) {
      float s = 0.f;
      #pragma unroll
      for (int g = 0; g < 8; ++g) s += PART[g][tid];
      PART[0][tid] = s;
    }
    __syncthreads();  // PART[0] + TEB(bt1) ready

    // ============ scatter (overlaps GEMM1(bt1) at wave level) =============
    {
      const int b  = bt0 >> 6;
      const int nm = NM[it];
      const float4 v = reinterpret_cast<const float4*>(&PART[0][0])[lane];
      for (int q = w; q < nm; q += 16) {
        int s = MATCH[it][q];
        reinterpret_cast<float4*>(out + ((size_t)(b * SS + s)) * 256)[lane] = v;
      }
    }
  }
}

extern "C" void kernel_launch(void* const* d_in, const int* in_sizes, int n_in,
                              void* d_out, int out_size, void* d_ws, size_t ws_size,
                              hipStream_t stream) {
  const int*   triples      = (const int*)d_in[1];
  const int*   sent_triples = (const int*)d_in[2];
  const float* emb_table    = (const float*)d_in[3];
  const float* W_trans      = (const float*)d_in[4];
  const float* b_trans      = (const float*)d_in[5];
  const float* W_ht         = (const float*)d_in[6];
  const float* b_ht         = (const float*)d_in[7];
  const float* W_rel        = (const float*)d_in[8];
  const float* b_rel        = (const float*)d_in[9];
  float* out = (float*)d_out;
  unsigned char* ws = (unsigned char*)d_ws;

  prep_kernel<<<32, 256, 0, stream>>>(W_trans, W_ht, W_rel, ws);

  fused_bt<<<BB * TT / 2, 1024, 0, stream>>>(
      triples, emb_table, b_trans, b_ht, b_rel, sent_triples, ws, out);
}

// Round 3
// 47.340 us; speedup vs baseline: 5.0316x; 5.0316x over previous
//
#include <hip/hip_runtime.h>
#include <cstdint>
#include <cstddef>

typedef short short8 __attribute__((ext_vector_type(8)));
typedef float f32x4 __attribute__((ext_vector_type(4)));

#define BB 16
#define SS 512
#define TT 64
#define LL 64
#define UU 128

// ws layout (bytes) — hi-only W fragments (no emb table)
#define WT_OFF    0u                      // W_trans frags: 32 x 1KB = 32KB
#define WHT_OFF   (WT_OFF + 32768u)       // W_ht frags: 64 x 1KB = 64KB
#define WREL_OFF  (WHT_OFF + 65536u)      // W_rel frags: 32 x 1KB = 32KB

__device__ __forceinline__ unsigned short f2bf(float x) {  // rtne f32->bf16
  unsigned u = __float_as_uint(x);
  unsigned r = ((u >> 16) & 1u) + 0x7FFFu;
  return (unsigned short)((u + r) >> 16);
}
__device__ __forceinline__ float bf2f(unsigned short h) {
  return __uint_as_float(((unsigned)h) << 16);
}
__device__ __forceinline__ float ftanh(float x) {  // 1 - 2/(e^2x+1)
  float e = __expf(2.0f * x);
  return 1.0f - __fdividef(2.0f, e + 1.0f);
}
// packed rtne pair convert: lo=cvt(a), hi=cvt(b)
__device__ __forceinline__ unsigned cvtpk(float a, float b) {
  unsigned r;
  asm("v_cvt_pk_bf16_f32 %0, %1, %2" : "=v"(r) : "v"(a), "v"(b));
  return r;
}
// 16-lane (DPP row) sum — pure VALU, no LDS pipe. After the 4 steps every
// lane holds the 16-lane sum (verified numerically in rounds 1-2).
__device__ __forceinline__ float row16_sum(float x) {
  x += __int_as_float(__builtin_amdgcn_update_dpp(0, __float_as_int(x), 0xB1, 0xF, 0xF, true));
  x += __int_as_float(__builtin_amdgcn_update_dpp(0, __float_as_int(x), 0x4E, 0xF, 0xF, true));
  x += __int_as_float(__builtin_amdgcn_update_dpp(0, __float_as_int(x), 0x141, 0xF, 0xF, true));
  x += __int_as_float(__builtin_amdgcn_update_dpp(0, __float_as_int(x), 0x140, 0xF, 0xF, true));
  return x;
}

// ---- prep: pack W into bf16 fragments (hi only). 32 blocks, ~1.3us. -------
// Frag (16x16x32, A/B symmetric): lane l holds W[kt*32+(l>>4)*8+j][nt*16+(l&15)].
// pairIdx=(kt*8+nt): [pairIdx*1024 + lane*16].
__global__ void prep_kernel(const float* __restrict__ Wt,
                            const float* __restrict__ Wht,
                            const float* __restrict__ Wrel,
                            unsigned char* __restrict__ ws) {
  int slot = blockIdx.x * 256 + threadIdx.x;      // 8192 slots
  const float* W;
  unsigned char* base;
  if (slot < 2048)      { W = Wt;   base = ws + WT_OFF; }
  else if (slot < 6144) { W = Wht;  base = ws + WHT_OFF;  slot -= 2048; }
  else                  { W = Wrel; base = ws + WREL_OFF; slot -= 6144; }
  int lane = slot & 63, pair = slot >> 6;
  int n  = (pair & 7) * 16 + (lane & 15);
  int k0 = (pair >> 3) * 32 + (lane >> 4) * 8;
  short8 hv;
  #pragma unroll
  for (int j = 0; j < 8; ++j)
    hv[j] = (short)f2bf(W[(size_t)(k0 + j) * UU + n]);
  *reinterpret_cast<short8*>(base + (size_t)pair * 1024 + lane * 16) = hv;
}

// ---- fused per-(b,t) kernel: 1024 blocks x 1024 threads (16 waves) ---------
// R0-verified structure. Wave split: GEMM1 wave w -> (nt = w&7, row-half
// rh = w>>3 owning 6 of 12 16-row tiles); GEMM2 wave w -> (nt = w&7,
// m-pair mh = (w>>3)*2).  TEB swizzle: logical 16B-chunk c16 of row r at
// physical chunk c16^(r&15).  Staging converts f32->bf16 in flight (cvt_pk),
// eliminating the separate prep conversion pass.
__launch_bounds__(1024, 8)
__global__ void fused_bt(const int* __restrict__ triples,
                         const float* __restrict__ emb_f32,
                         const float* __restrict__ b_trans,
                         const float* __restrict__ b_ht,
                         const float* __restrict__ b_rel,
                         const int* __restrict__ sent_triples,
                         const unsigned char* __restrict__ wsr,
                         float* __restrict__ out) {
  __shared__ unsigned short TEB[192 * 128];    // 48KB: emb staging -> te
  __shared__ float EWt[8][64];                 // e_weight partials; MATCH overlay
  __shared__ float ALPHA[64];
  __shared__ float PART[8][256];               // TOKs overlay (early) + partials
  int* TOKs = reinterpret_cast<int*>(&PART[0][0]);   // 768B of row 0

  const int tid  = threadIdx.x;
  const int bt   = blockIdx.x;
  const int w    = tid >> 6;      // wave id 0..15
  const int lane = tid & 63;
  const int li   = lane & 15;
  const int lg   = lane >> 4;
  const int nt   = w & 7;         // u-tile of 16
  const int rh   = w >> 3;        // 0/1

  // sent_triples prefetch: independent, issued at entry, used in the tail
  int sidx = 0;
  if (tid < SS) sidx = sent_triples[(size_t)(bt >> 6) * SS + tid];

  if (tid < 48)
    reinterpret_cast<int4*>(TOKs)[tid] =
        reinterpret_cast<const int4*>(triples + (size_t)bt * 192)[tid];

  const unsigned char* wtb  = wsr + WT_OFF;
  const unsigned char* whtb = wsr + WHT_OFF;
  const unsigned char* wrlb = wsr + WREL_OFF;
  const float bhv   = b_ht[nt * 16 + li];
  const float brlv  = b_rel[nt * 16 + li];
  const float4 btr4 = *reinterpret_cast<const float4*>(b_trans + nt * 16 + lg * 4);
  __syncthreads();  // TOKs ready

  // ---- stage ALL 192 emb rows into TEB (3 slots/thread, loads first) ----
  // f32 gather + in-flight cvt_pk to bf16; swizzle applied on source chunk.
  {
    float4 xv[3], yv[3];
    #pragma unroll
    for (int j = 0; j < 3; ++j) {
      int o = tid + j * 1024;             // 3072 slots = 192 rows x 16 chunks
      int row = o >> 4, pc = o & 15;
      int clog = pc ^ (row & 15);
      const float* fb = emb_f32 + (size_t)TOKs[row] * UU + clog * 8;
      xv[j] = *reinterpret_cast<const float4*>(fb);
      yv[j] = *reinterpret_cast<const float4*>(fb + 4);
    }
    #pragma unroll
    for (int j = 0; j < 3; ++j) {
      int o = tid + j * 1024;
      uint4 pk = { cvtpk(xv[j].x, xv[j].y), cvtpk(xv[j].z, xv[j].w),
                   cvtpk(yv[j].x, yv[j].y), cvtpk(yv[j].z, yv[j].w) };
      *reinterpret_cast<uint4*>(&TEB[o * 8]) = pk;
    }
  }

  // GEMM1 A-frags (W_trans^T), register-resident (hi only), loaded post-staging
  short8 B1h[4];
  #pragma unroll
  for (int kt = 0; kt < 4; ++kt)
    B1h[kt] = *reinterpret_cast<const short8*>(
        wtb + (size_t)(kt * 8 + nt) * 1024 + lane * 16);
  __syncthreads();  // staging complete

  const int cc8 = nt * 2 + (lg >> 1);  // u-chunk of this thread's u-quad
  const int hb8 = (lg & 1) << 3;       // byte offset within 16B chunk

  // ============ GEMM1 read phase: 6 tiles x 4 kt, barrier-free ============
  f32x4 acc[6];
  #pragma unroll
  for (int q = 0; q < 6; ++q) acc[q] = f32x4{0.f, 0.f, 0.f, 0.f};

  #pragma unroll
  for (int kt = 0; kt < 4; ++kt) {
    #pragma unroll
    for (int q = 0; q < 6; ++q) {
      // B-frag: lane reads emb row (rh*6+q)*16+li, k-chunk kt*4+lg
      const short8 b = *reinterpret_cast<const short8*>(
          &TEB[((rh * 6 + q) * 16 + li) * 128 + (((kt * 4 + lg) ^ li) << 3)]);
      acc[q] = __builtin_amdgcn_mfma_f32_16x16x32_bf16(B1h[kt], b, acc[q], 0, 0, 0);
    }
  }
  __syncthreads();  // ALL emb reads complete before any te overwrite

  // ============ GEMM1 write phase: te in one pass =========================
  #pragma unroll
  for (int q = 0; q < 6; ++q) {
    int row = (rh * 6 + q) * 16 + li;    // row & 15 == li
    float v0 = ftanh(acc[q][0] + btr4.x);
    float v1 = ftanh(acc[q][1] + btr4.y);
    float v2 = ftanh(acc[q][2] + btr4.z);
    float v3 = ftanh(acc[q][3] + btr4.w);
    uint2 pk = { cvtpk(v0, v1), cvtpk(v2, v3) };
    *reinterpret_cast<uint2*>(
        reinterpret_cast<char*>(TEB) + row * 256 +
        (((cc8 ^ li) << 4) | hb8)) = pk;
  }

  // prefetch GEMM2 first W-frag before the barrier
  short8 Wc = *reinterpret_cast<const short8*>(
      whtb + (size_t)nt * 1024 + lane * 16);
  __syncthreads();  // te complete

  // ============ GEMM2: ht_t / rel_t / e_weight (2 m-tiles per wave) =======
  // head = te row 3l+0, rel = 3l+1, tail = 3l+2  (l = m*16 + li)
  const int mh = rh * 2;
  f32x4 accH[2] = {{0.f,0.f,0.f,0.f},{0.f,0.f,0.f,0.f}};
  f32x4 accR[2] = {{0.f,0.f,0.f,0.f},{0.f,0.f,0.f,0.f}};

  #pragma unroll
  for (int kt = 0; kt < 8; ++kt) {   // head_tail: K=256
    short8 Wn;
    if (kt < 7)
      Wn = *reinterpret_cast<const short8*>(
          whtb + (size_t)((kt + 1) * 8 + nt) * 1024 + lane * 16);
    else
      Wn = *reinterpret_cast<const short8*>(
          wrlb + (size_t)nt * 1024 + lane * 16);
    const int koff = (kt < 4) ? 0 : 2;
    const int c16  = (kt & 3) * 4 + lg;
    #pragma unroll
    for (int mi = 0; mi < 2; ++mi) {
      const int row = 48 * (mh + mi) + 3 * li + koff;
      const short8 a = *reinterpret_cast<const short8*>(
          &TEB[row * 128 + ((c16 ^ (row & 15)) << 3)]);
      accH[mi] = __builtin_amdgcn_mfma_f32_16x16x32_bf16(a, Wc, accH[mi], 0, 0, 0);
    }
    Wc = Wn;
  }
  #pragma unroll
  for (int kt = 0; kt < 4; ++kt) {   // relation: K=128, rows 3l+1
    short8 Wn;
    if (kt < 3)
      Wn = *reinterpret_cast<const short8*>(
          wrlb + (size_t)((kt + 1) * 8 + nt) * 1024 + lane * 16);
    const int c16 = kt * 4 + lg;
    #pragma unroll
    for (int mi = 0; mi < 2; ++mi) {
      const int row = 48 * (mh + mi) + 3 * li + 1;
      const short8 a = *reinterpret_cast<const short8*>(
          &TEB[row * 128 + ((c16 ^ (row & 15)) << 3)]);
      accR[mi] = __builtin_amdgcn_mfma_f32_16x16x32_bf16(a, Wc, accR[mi], 0, 0, 0);
    }
    Wc = Wn;
  }

  // e_weight partials: l = (mh+mi)*16 + lg*4 + r; DPP-reduce over 16 u lanes
  #pragma unroll
  for (int mi = 0; mi < 2; ++mi) {
    #pragma unroll
    for (int r = 0; r < 4; ++r) {
      float p = ftanh(accH[mi][r] + bhv) * (accR[mi][r] + brlv);
      p = row16_sum(p);
      if (li == 0) EWt[nt][(mh + mi) * 16 + lg * 4 + r] = p;
    }
  }
  __syncthreads();

  // ============ softmax over L=64 (wave 0) =================================
  if (tid < 64) {
    float e = 0.f;
    #pragma unroll
    for (int n = 0; n < 8; ++n) e += EWt[n][tid];
    float mx = e;
    #pragma unroll
    for (int off = 32; off > 0; off >>= 1)
      mx = fmaxf(mx, __shfl_xor(mx, off, 64));
    float ex = __expf(e - mx);
    float sm = ex;
    #pragma unroll
    for (int off = 32; off > 0; off >>= 1)
      sm += __shfl_xor(sm, off, 64);
    ALPHA[tid] = ex / sm;
  }
  __syncthreads();

  // ============ weighted sum: paired-bf16 b32 reads, 8 l's per thread ======
  {
    int cp  = tid & 127, lgp = tid >> 7;   // col-pair, l-group (8 l's)
    int c0  = cp << 1;
    int k   = (c0 >> 7) << 1;              // head rows 3l, tail rows 3l+2
    int cc  = c0 & 127;
    int w8  = cc >> 3, bofs = (cc & 7) << 1;
    float4 a03 = *reinterpret_cast<const float4*>(&ALPHA[lgp * 8]);
    float4 a47 = *reinterpret_cast<const float4*>(&ALPHA[lgp * 8 + 4]);
    float o0 = 0.f, o1 = 0.f;
    #pragma unroll
    for (int j = 0; j < 8; ++j) {
      int l = lgp * 8 + j;
      int row = 3 * l + k;
      unsigned u = *reinterpret_cast<const unsigned*>(
          reinterpret_cast<const char*>(TEB) + row * 256 +
          (((w8 ^ (row & 15)) << 4) | bofs));
      float al = (j < 4) ? a03[j] : a47[j - 4];
      o0 = fmaf(al, __uint_as_float(u << 16), o0);
      o1 = fmaf(al, __uint_as_float(u & 0xFFFF0000u), o1);
    }
    *reinterpret_cast<float2*>(&PART[lgp][c0]) = make_float2(o0, o1);
  }
  __syncthreads();  // all ALPHA reads + PART writes complete

  // MATCH list overlays dead EWt (512 ints); counter overlays dead ALPHA[0].
  int* MATCH = reinterpret_cast<int*>(&EWt[0][0]);
  int* NM    = reinterpret_cast<int*>(&ALPHA[0]);
  if (tid < 256) {
    float s = 0.f;
    #pragma unroll
    for (int g = 0; g < 8; ++g) s += PART[g][tid];
    PART[0][tid] = s;
  }
  if (tid == 0) *NM = 0;
  __syncthreads();

  // ============ cooperative scatter: wave-per-row coalesced copies =========
  {
    int b = bt >> 6, t = bt & 63;
    if (tid < SS && sidx == t) {
      int slot = atomicAdd(NM, 1);
      MATCH[slot] = tid;
    }
    __syncthreads();
    const int nm = *NM;
    const float4 v = reinterpret_cast<const float4*>(&PART[0][0])[lane];
    for (int q = w; q < nm; q += 16) {
      int s = MATCH[q];
      reinterpret_cast<float4*>(out + ((size_t)(b * SS + s)) * 256)[lane] = v;
    }
  }
}

extern "C" void kernel_launch(void* const* d_in, const int* in_sizes, int n_in,
                              void* d_out, int out_size, void* d_ws, size_t ws_size,
                              hipStream_t stream) {
  const int*   triples      = (const int*)d_in[1];
  const int*   sent_triples = (const int*)d_in[2];
  const float* emb_table    = (const float*)d_in[3];
  const float* W_trans      = (const float*)d_in[4];
  const float* b_trans      = (const float*)d_in[5];
  const float* W_ht         = (const float*)d_in[6];
  const float* b_ht         = (const float*)d_in[7];
  const float* W_rel        = (const float*)d_in[8];
  const float* b_rel        = (const float*)d_in[9];
  float* out = (float*)d_out;
  unsigned char* ws = (unsigned char*)d_ws;

  prep_kernel<<<32, 256, 0, stream>>>(W_trans, W_ht, W_rel, ws);

  fused_bt<<<BB * TT, 1024, 0, stream>>>(
      triples, emb_table, b_trans, b_ht, b_rel, sent_triples, ws, out);
}